// Round 1
// baseline (46.856 us; speedup 1.0000x reference)
//
#include <hip/hip_runtime.h>

// GraphSage fused gather + mean-aggregate + dual matvec + ReLU
// Shapes: adj (16,32,32,16) i32; emb (1000001,128) f32; W,b (128,128) f32
// out (16,32,32,128) f32.  Rows = 16*32*32 = 16384, 16 rows per block.

constexpr int DIM   = 128;
constexpr int KN    = 16;     // neighbors incl. self
constexpr int RPB   = 16;     // rows per block
constexpr int NROWS = 16 * 32 * 32;  // 16384

__global__ __launch_bounds__(256, 2)
void graphsage_fused(const int* __restrict__ adj,
                     const float* __restrict__ emb,
                     const float* __restrict__ W,
                     const float* __restrict__ Bm,
                     float* __restrict__ out)
{
    __shared__ float xs_lds[RPB][DIM];   // x_self
    __shared__ float ag_lds[RPB][DIM];   // mean of neighbors
    __shared__ int   idx_lds[RPB * KN];

    const int t    = threadIdx.x;
    const int row0 = blockIdx.x * RPB;

    // stage the 256 adjacency indices for this block's 16 rows
    idx_lds[t] = adj[row0 * KN + t];
    __syncthreads();

    // ---- Phase A: gather + mean ----
    // thread t handles row r = t>>4, dim chunk dbase = (t&15)*8  (8 floats)
    {
        const int r     = t >> 4;
        const int dbase = (t & 15) * 8;
        float4 x0, x1;
        float4 a0 = make_float4(0.f, 0.f, 0.f, 0.f);
        float4 a1 = make_float4(0.f, 0.f, 0.f, 0.f);
        #pragma unroll
        for (int k = 0; k < KN; ++k) {
            const int e = idx_lds[r * KN + k];
            const float4* p =
                reinterpret_cast<const float4*>(emb + (size_t)e * DIM + dbase);
            const float4 v0 = p[0];
            const float4 v1 = p[1];
            if (k == 0) { x0 = v0; x1 = v1; }
            else {
                a0.x += v0.x; a0.y += v0.y; a0.z += v0.z; a0.w += v0.w;
                a1.x += v1.x; a1.y += v1.y; a1.z += v1.z; a1.w += v1.w;
            }
        }
        const float s = 1.0f / 15.0f;
        a0.x *= s; a0.y *= s; a0.z *= s; a0.w *= s;
        a1.x *= s; a1.y *= s; a1.z *= s; a1.w *= s;
        *reinterpret_cast<float4*>(&xs_lds[r][dbase])     = x0;
        *reinterpret_cast<float4*>(&xs_lds[r][dbase + 4]) = x1;
        *reinterpret_cast<float4*>(&ag_lds[r][dbase])     = a0;
        *reinterpret_cast<float4*>(&ag_lds[r][dbase + 4]) = a1;
    }
    __syncthreads();

    // ---- Phase B: out[row][h] = relu(agg·W[:,h] + xs·b[:,h]) ----
    // thread t: cols {h, h+64} with h = t&63; rows rb..rb+3 with rb = (t>>6)*4
    {
        const int h  = t & 63;
        const int rb = (t >> 6) * 4;
        float acc[4][2] = {};
        for (int d0 = 0; d0 < DIM; d0 += 4) {
            float4 ag[4], xs[4];
            #pragma unroll
            for (int r = 0; r < 4; ++r) {  // wave-uniform LDS broadcasts
                ag[r] = *reinterpret_cast<const float4*>(&ag_lds[rb + r][d0]);
                xs[r] = *reinterpret_cast<const float4*>(&xs_lds[rb + r][d0]);
            }
            #pragma unroll
            for (int dd = 0; dd < 4; ++dd) {
                const float w0 = W [(d0 + dd) * DIM + h];
                const float w1 = W [(d0 + dd) * DIM + h + 64];
                const float b0 = Bm[(d0 + dd) * DIM + h];
                const float b1 = Bm[(d0 + dd) * DIM + h + 64];
                #pragma unroll
                for (int r = 0; r < 4; ++r) {
                    const float a = (&ag[r].x)[dd];
                    const float x = (&xs[r].x)[dd];
                    acc[r][0] += a * w0 + x * b0;
                    acc[r][1] += a * w1 + x * b1;
                }
            }
        }
        #pragma unroll
        for (int r = 0; r < 4; ++r) {
            float* o = out + (size_t)(row0 + rb + r) * DIM + h;
            o[0]  = fmaxf(acc[r][0], 0.0f);
            o[64] = fmaxf(acc[r][1], 0.0f);
        }
    }
}

extern "C" void kernel_launch(void* const* d_in, const int* in_sizes, int n_in,
                              void* d_out, int out_size, void* d_ws, size_t ws_size,
                              hipStream_t stream) {
    const int*   adj = (const int*)  d_in[0];
    const float* emb = (const float*)d_in[1];
    const float* W   = (const float*)d_in[2];
    const float* b   = (const float*)d_in[3];
    float*       out = (float*)d_out;

    dim3 grid(NROWS / RPB);   // 1024 blocks
    dim3 block(256);
    graphsage_fused<<<grid, block, 0, stream>>>(adj, emb, W, b, out);
}